// Round 9
// baseline (162.333 us; speedup 1.0000x reference)
//
#include <hip/hip_runtime.h>

#define EPSF 1e-5f

typedef int    int4v   __attribute__((ext_vector_type(4)));
typedef float  float4v __attribute__((ext_vector_type(4)));

// ---------- ws layout (weights/constants only; intermediates live in LDS) ----------
#define W1P_OFF  0
#define W3P_OFF  55296
#define W2D_OFF  110592
#define S1B1_OFF 202752
#define S2B2_OFF 207360
#define S3B3_OFF 211968

// LDS stride (bytes) for nibble-packed 576-ch rows: 288 B + 8 pad = 296.
// 74 words === 10 mod 32: 16-lane stride-296 dword gathers hit 16 distinct banks
// (measured r6: best conflict count of the tested strides).
#define H1S 296
#define H2S 296

__device__ __forceinline__ float lsq_q(float v, float a) {
    float t = v / a;                       // real division (weight alphas not pow2)
    t = fminf(fmaxf(t, -8.0f), 7.0f);
    return rintf(t);                       // RNE == jnp.round
}

__device__ __forceinline__ long q8pack_w(const float* w, int base, float a) {
    unsigned long long v = 0;
    #pragma unroll
    for (int j = 0; j < 8; ++j) {
        int q = (int)lsq_q(w[base + j], a);
        v |= (unsigned long long)(q & 255) << (8 * j);
    }
    return (long)v;
}

__device__ __forceinline__ long q8pack_wp(const float* w, int base, const int* idx, float a) {
    unsigned long long v = 0;
    #pragma unroll
    for (int j = 0; j < 8; ++j) {
        int q = (int)lsq_q(w[base + idx[j]], a);
        v |= (unsigned long long)(q & 255) << (8 * j);
    }
    return (long)v;
}

// ---------------- prep: quantize/pack weights + fused epilogue constants ----------------
// i8 MFMA 16x16x32 fragment layout (HW-verified r2-r8): lane l holds 8 k-bytes
// k = (l>>4)*8 + j at m/n = l&15;  D: col = l&15, row = (l>>4)*4 + reg.
__global__ __launch_bounds__(256)
void prep_w(const float* __restrict__ w1, const float* __restrict__ w2,
            const float* __restrict__ w3,
            const float* aw1, const float* ax1, const float* ax2,
            const float* aw2, const float* ax3, const float* aw3,
            const float* __restrict__ g1, const float* __restrict__ b1,
            const float* __restrict__ m1, const float* __restrict__ v1,
            const float* __restrict__ g2, const float* __restrict__ b2,
            const float* __restrict__ m2, const float* __restrict__ v2,
            const float* __restrict__ g3, const float* __restrict__ b3,
            const float* __restrict__ m3, const float* __restrict__ v3,
            long* __restrict__ w1p, long* __restrict__ w3p,
            long* __restrict__ w2d,
            float* __restrict__ s1b1, float* __restrict__ s2b2,
            float* __restrict__ s3b3) {
    int id = blockIdx.x * 256 + threadIdx.x;
    if (id < 6912) {                        // w1p: ct 0..35, kc 0..2 (linear k)
        int l = id & 63, t = id >> 6;
        int kc = t % 3, ct = t / 3;
        int co = ct * 16 + (l & 15);
        int ci0 = kc * 32 + (l >> 4) * 8;
        w1p[id] = q8pack_w(w1, co * 96 + ci0, aw1[0]);
    } else if (id < 13824) {                // w3p: ct 0..5, kc 0..17, nibble-perm k
        int i = id - 6912;
        int l = i & 63, t = i >> 6;
        int kc = t % 18, ct = t / 18;
        int co = ct * 16 + (l & 15);
        int ci0 = kc * 32 + (l >> 4) * 8;
        const int perm[8] = {0, 2, 4, 6, 1, 3, 5, 7};   // lo/hi nibble unpack order
        w3p[i] = q8pack_wp(w3, co * 576 + ci0, perm, aw3[0]);
    } else if (id < 25344) {                // w2d: (ct*5 + kc)*64 + l
        int i = id - 13824;
        int l = i & 63, t = i >> 6;
        int kc = t % 5, ct = t / 5;
        int quad = l >> 4, m = l & 15;
        int tap = kc * 2 + (quad >> 1);
        unsigned long long v = 0;
        if (tap <= 8) {
            int mh = m - (quad & 1) * 8;    // lane's channel within this quad's octet?
            if (mh >= 0 && mh < 8) {
                // byte j whose k-channel c' = (quad&1)*8 + 2*(j&3) + (j>>2) equals m
                int j = (mh >> 1) | ((mh & 1) << 2);
                int q = (int)lsq_q(w2[(ct * 16 + m) * 9 + tap], aw2[0]);
                v = (unsigned long long)(unsigned)(q & 255) << (8 * j);
            }
        }
        w2d[i] = (long)v;
    } else if (id < 25920) {                // conv1 fused constants
        int c = id - 25344;
        float s = g1[c] / sqrtf(v1[c] + EPSF);
        float A = aw1[0] * ax1[0];
        float inv = 1.0f / ax2[0];          // exact (alpha = pow2)
        s1b1[c] = A * s * inv;
        s1b1[576 + c] = (b1[c] - m1[c] * s) * inv;
    } else if (id < 26496) {                // dw fused constants
        int c = id - 25920;
        float s = g2[c] / sqrtf(v2[c] + EPSF);
        float A = ax2[0] * aw2[0];
        float inv = 1.0f / ax3[0];
        s2b2[c] = A * s * inv;
        s2b2[576 + c] = (b2[c] - m2[c] * s) * inv;
    } else if (id < 26592) {                // conv3 fused constants
        int c = id - 26496;
        float s = g3[c] / sqrtf(v3[c] + EPSF);
        float A = ax3[0] * aw3[0];
        s3b3[c] = A * s;
        s3b3[96 + c] = b3[c] - m3[c] * s;
    }
}

// ---------------- fused conv1 -> dw(MFMA) -> conv3, block = (batch, 1 output row) ----
// ~36 KB LDS -> 4 blocks/CU resident; grid 896 -> 3.5 blocks/CU (TLP is the fix for
// the r6-r8 latency plateau).  Both intermediates nibble-packed (values in [0,7]).
__global__ __launch_bounds__(448, 7)
void fused_k(const float* __restrict__ x, const long* __restrict__ w1p,
             const long* __restrict__ w2d, const long* __restrict__ w3p,
             const float* __restrict__ ax1,
             const float* __restrict__ s1b1, const float* __restrict__ s2b2,
             const float* __restrict__ s3b3, float* __restrict__ out) {
    __shared__ unsigned char h1[90 * H1S];   // 3 img rows x 30 halo cols, nibbles (26.6 KB)
    __shared__ unsigned char h2[32 * H2S];   // 28 pos + 4 pad, nibbles (9.5 KB)
    const int tid = threadIdx.x;
    const int w = tid >> 6, l = tid & 63;
    const int quad = l >> 4, c16 = l & 15;
    const int qh = quad >> 1, ql = quad & 1;
    const int b = blockIdx.x;          // batch 0..31
    const int r = blockIdx.y;          // output row 0..27

    // ---- Phase A: conv1 (i8 MFMA, A=weights B=acts) -> h1 nibbles ----
    if (w < 6) {                                     // 6 pos-tiles of 16 cover 84 slab pos
        const int sp = w * 16 + c16;                 // 0..95 (84..95 dead)
        const int tr = sp / 28, col = sp - tr * 28;  // tr 0..3 (3 = dead)
        const int ir = r - 1 + tr;
        const bool vrow = (unsigned)ir < 28u;
        const bool vpos = sp < 84;
        const int p = min(max(ir, 0), 27) * 28 + col;
        const float inv1 = 1.0f / ax1[0];            // exact for pow2 alpha

        long bfr[3];
        #pragma unroll
        for (int kc = 0; kc < 3; ++kc) {             // quantize 8 input ch per quad
            const float* xs = x + (b * 96 + kc * 32 + quad * 8) * 784 + p;
            unsigned long long v = 0;
            #pragma unroll
            for (int j = 0; j < 8; ++j) {
                float t = xs[j * 784] * inv1;
                t = fminf(fmaxf(t, -8.0f), 7.0f);
                int q = (int)rintf(t);
                v |= (unsigned long long)(q & 255) << (8 * j);
            }
            bfr[kc] = (long)v;
        }
        const int pos_h = tr * 30 + col + 1;         // halo-extended slab index
        #pragma unroll 4
        for (int ct = 0; ct < 36; ++ct) {
            int4v acc; acc[0] = 0; acc[1] = 0; acc[2] = 0; acc[3] = 0;
            #pragma unroll
            for (int kc = 0; kc < 3; ++kc)
                acc = __builtin_amdgcn_mfma_i32_16x16x32_i8(
                    w1p[(ct * 3 + kc) * 64 + l], bfr[kc], acc, 0, 0, 0);
            const int co0 = ct * 16 + quad * 4;      // 4 consecutive co per lane
            float4v S = *(const float4v*)(s1b1 + co0);
            float4v B = *(const float4v*)(s1b1 + 576 + co0);
            int pk = 0;
            #pragma unroll
            for (int rr = 0; rr < 4; ++rr) {
                float t = fmaf((float)acc[rr], S[rr], B[rr]);
                t = fminf(fmaxf(t, 0.0f), 7.0f);     // ReLU6 + quant-clip fused
                pk |= ((int)rintf(t)) << (4 * rr);   // nibble pack (values 0..7)
            }
            pk = vrow ? pk : 0;                      // halo rows outside image = 0
            if (vpos)
                *(unsigned short*)(h1 + pos_h * H1S + ct * 8 + quad * 2) = (unsigned short)pk;
        }
    }
    // zero halo COLUMNS (cols 0 and 29 of the 3 rows): 3 x 2 x 72 dwords = 432 tasks
    if (tid < 432) {
        const int tr = tid / 144, rem = tid - tr * 144;
        const int colh = (rem / 72) * 29, word = rem - (rem / 72) * 72;
        *(int*)(h1 + (tr * 30 + colh) * H1S + word * 4) = 0;
    }
    __syncthreads();

    // ---- Phase B: 3x3 depthwise as block-diagonal i8 MFMA (K=144, 5 chunks) ----
    int boff[5];                                     // per-lane tap offsets (hoisted)
    #pragma unroll
    for (int kc = 0; kc < 5; ++kc) {
        int tap = kc * 2 + qh;
        tap = min(tap, 8);                           // tap 9 has zero weight in w2d
        const int dh = tap / 3 - 1, dc = tap - (tap / 3) * 3 - 1;
        boff[kc] = (dh * 30 + dc) * H1S;
    }
    for (int t = w; t < 72; t += 7) {                // 2 pos-tiles x 36 ch-tiles
        const int pt = (t >= 36) ? 1 : 0, ct = t - pt * 36;
        const int pos = pt * 16 + c16;               // 0..31 (28..31 dead)
        const int col = min(pos, 27);
        const unsigned char* sbase = h1 + (30 + col + 1) * H1S + ct * 8 + ql * 4;
        int4v acc; acc[0] = 0; acc[1] = 0; acc[2] = 0; acc[3] = 0;
        #pragma unroll
        for (int kc = 0; kc < 5; ++kc) {
            const unsigned v = *(const unsigned*)(sbase + boff[kc]);
            const long bf = (long)((((unsigned long long)((v >> 4) & 0x0F0F0F0Fu)) << 32)
                                   | (v & 0x0F0F0F0Fu));
            acc = __builtin_amdgcn_mfma_i32_16x16x32_i8(
                w2d[(ct * 5 + kc) * 64 + l], bf, acc, 0, 0, 0);
        }
        const int c0 = ct * 16 + quad * 4;
        float4v S = *(const float4v*)(s2b2 + c0);
        float4v B = *(const float4v*)(s2b2 + 576 + c0);
        int pk = 0;
        #pragma unroll
        for (int rr = 0; rr < 4; ++rr) {
            float tt = fmaf((float)acc[rr], S[rr], B[rr]);
            tt = fminf(fmaxf(tt, 0.0f), 7.0f);
            pk |= ((int)rintf(tt)) << (4 * rr);      // nibble pack
        }
        if (pos < 28)
            *(unsigned short*)(h2 + pos * H2S + ct * 8 + quad * 2) = (unsigned short)pk;
    }
    __syncthreads();

    // ---- Phase C: conv3 (i8 MFMA, A=h2 nibbles B=perm'd weights) + BN + residual ----
    for (int t = w; t < 12; t += 7) {                // 2 pos-tiles x 6 co-tiles
        const int nt = t / 6, ct = t - nt * 6;
        const unsigned char* arow = h2 + (nt * 16 + c16) * H2S + quad * 4;
        int4v acc; acc[0] = 0; acc[1] = 0; acc[2] = 0; acc[3] = 0;
        #pragma unroll 6
        for (int kc = 0; kc < 18; ++kc) {
            const unsigned v = *(const unsigned*)(arow + kc * 16);
            const long a = (long)((((unsigned long long)((v >> 4) & 0x0F0F0F0Fu)) << 32)
                                  | (v & 0x0F0F0F0Fu));
            acc = __builtin_amdgcn_mfma_i32_16x16x32_i8(
                a, w3p[(ct * 18 + kc) * 64 + l], acc, 0, 0, 0);
        }
        const int nloc = nt * 16 + quad * 4;          // 4 consecutive positions
        if (nloc < 28) {
            const int co = ct * 16 + c16;
            const float S = s3b3[co], Bv = s3b3[96 + co];
            const int off = (b * 96 + co) * 784 + r * 28 + nloc;  // 16B-aligned
            const float4v xr = *(const float4v*)(x + off);
            float4v o;
            #pragma unroll
            for (int rr = 0; rr < 4; ++rr)
                o[rr] = fmaf((float)acc[rr], S, Bv) + xr[rr];
            *(float4v*)(out + off) = o;
        }
    }
}

extern "C" void kernel_launch(void* const* d_in, const int* in_sizes, int n_in,
                              void* d_out, int out_size, void* d_ws, size_t ws_size,
                              hipStream_t stream) {
    const float* x   = (const float*)d_in[0];
    const float* w1  = (const float*)d_in[1];
    const float* w2  = (const float*)d_in[2];
    const float* w3  = (const float*)d_in[3];
    const float* aw1 = (const float*)d_in[4];
    const float* ax1 = (const float*)d_in[5];
    const float* g1  = (const float*)d_in[6];
    const float* b1  = (const float*)d_in[7];
    const float* m1  = (const float*)d_in[8];
    const float* v1  = (const float*)d_in[9];
    const float* aw2 = (const float*)d_in[10];
    const float* ax2 = (const float*)d_in[11];
    const float* g2  = (const float*)d_in[12];
    const float* b2  = (const float*)d_in[13];
    const float* m2  = (const float*)d_in[14];
    const float* v2  = (const float*)d_in[15];
    const float* aw3 = (const float*)d_in[16];
    const float* ax3 = (const float*)d_in[17];
    const float* g3  = (const float*)d_in[18];
    const float* b3  = (const float*)d_in[19];
    const float* m3  = (const float*)d_in[20];
    const float* v3  = (const float*)d_in[21];

    char* ws = (char*)d_ws;
    long* w1p = (long*)(ws + W1P_OFF);
    long* w3p = (long*)(ws + W3P_OFF);
    long* w2d = (long*)(ws + W2D_OFF);
    float* s1b1 = (float*)(ws + S1B1_OFF);
    float* s2b2 = (float*)(ws + S2B2_OFF);
    float* s3b3 = (float*)(ws + S3B3_OFF);

    float* out = (float*)d_out;

    prep_w<<<104, 256, 0, stream>>>(w1, w2, w3, aw1, ax1, ax2, aw2, ax3, aw3,
                                    g1, b1, m1, v1, g2, b2, m2, v2, g3, b3, m3, v3,
                                    w1p, w3p, w2d, s1b1, s2b2, s3b3);
    dim3 grid(32, 28);
    fused_k<<<grid, 448, 0, stream>>>(x, w1p, w2d, w3p, ax1, s1b1, s2b2, s3b3, out);
}

// Round 10
// 157.471 us; speedup vs baseline: 1.0309x; 1.0309x over previous
//
#include <hip/hip_runtime.h>

#define EPSF 1e-5f

typedef int    int4v   __attribute__((ext_vector_type(4)));
typedef float  float4v __attribute__((ext_vector_type(4)));

// ---------- ws layout ----------
// qh2s : u16 [144 slots][25088 n]  nibble-packed dw output; slot=ch/4, 4 ch per ushort
// w1p  : i64 [36*3*64]   conv1 A-fragments (m=co)
// w3p  : i64 [6*18*64]   conv3 B-fragments (n=co, nibble-perm k folded)
// w2d  : i64 [36*5*64]   dw diagonal A-fragments
#define QH2S_OFF 0
#define W1P_OFF  7225344
#define W3P_OFF  7280640
#define W2D_OFF  7335936
#define S1B1_OFF 7428096
#define S2B2_OFF 7432704
#define S3B3_OFF 7437312

// K1 LDS: h1 nibble rows of 288 ch (half) = 144 B + 8 pad = 152 (38 w === 6 mod 32,
// gcd 2 -> 16-lane gathers cover 16 distinct banks; mimics the measured-good r6 pattern).
#define H1S 152

__device__ __forceinline__ float lsq_q(float v, float a) {
    float t = v / a;                       // real division (weight alphas not pow2)
    t = fminf(fmaxf(t, -8.0f), 7.0f);
    return rintf(t);                       // RNE == jnp.round
}

__device__ __forceinline__ long q8pack_w(const float* w, int base, float a) {
    unsigned long long v = 0;
    #pragma unroll
    for (int j = 0; j < 8; ++j) {
        int q = (int)lsq_q(w[base + j], a);
        v |= (unsigned long long)(q & 255) << (8 * j);
    }
    return (long)v;
}

__device__ __forceinline__ long q8pack_wp(const float* w, int base, const int* idx, float a) {
    unsigned long long v = 0;
    #pragma unroll
    for (int j = 0; j < 8; ++j) {
        int q = (int)lsq_q(w[base + idx[j]], a);
        v |= (unsigned long long)(q & 255) << (8 * j);
    }
    return (long)v;
}

// ---------------- prep: quantize/pack weights + fused epilogue constants ----------------
// i8 MFMA 16x16x32 fragment layout (HW-verified r2-r9): lane l holds 8 k-bytes
// k = (l>>4)*8 + j at m/n = l&15;  D: col = l&15, row = (l>>4)*4 + reg.
__global__ __launch_bounds__(256)
void prep_w(const float* __restrict__ w1, const float* __restrict__ w2,
            const float* __restrict__ w3,
            const float* aw1, const float* ax1, const float* ax2,
            const float* aw2, const float* ax3, const float* aw3,
            const float* __restrict__ g1, const float* __restrict__ b1,
            const float* __restrict__ m1, const float* __restrict__ v1,
            const float* __restrict__ g2, const float* __restrict__ b2,
            const float* __restrict__ m2, const float* __restrict__ v2,
            const float* __restrict__ g3, const float* __restrict__ b3,
            const float* __restrict__ m3, const float* __restrict__ v3,
            long* __restrict__ w1p, long* __restrict__ w3p,
            long* __restrict__ w2d,
            float* __restrict__ s1b1, float* __restrict__ s2b2,
            float* __restrict__ s3b3) {
    int id = blockIdx.x * 256 + threadIdx.x;
    if (id < 6912) {                        // w1p: ct 0..35, kc 0..2 (linear k)
        int l = id & 63, t = id >> 6;
        int kc = t % 3, ct = t / 3;
        int co = ct * 16 + (l & 15);
        int ci0 = kc * 32 + (l >> 4) * 8;
        w1p[id] = q8pack_w(w1, co * 96 + ci0, aw1[0]);
    } else if (id < 13824) {                // w3p: ct 0..5, kc 0..17, nibble-perm k
        int i = id - 6912;
        int l = i & 63, t = i >> 6;
        int kc = t % 18, ct = t / 18;
        int co = ct * 16 + (l & 15);
        int ci0 = kc * 32 + (l >> 4) * 8;
        const int perm[8] = {0, 2, 4, 6, 1, 3, 5, 7};   // lo/hi nibble unpack order
        w3p[i] = q8pack_wp(w3, co * 576 + ci0, perm, aw3[0]);
    } else if (id < 25344) {                // w2d: (ct*5 + kc)*64 + l
        int i = id - 13824;
        int l = i & 63, t = i >> 6;
        int kc = t % 5, ct = t / 5;
        int quad = l >> 4, m = l & 15;
        int tap = kc * 2 + (quad >> 1);
        unsigned long long v = 0;
        if (tap <= 8) {
            int mh = m - (quad & 1) * 8;    // lane's channel within this quad's octet?
            if (mh >= 0 && mh < 8) {
                // byte j whose k-channel c' = (quad&1)*8 + 2*(j&3) + (j>>2) equals m
                int j = (mh >> 1) | ((mh & 1) << 2);
                int q = (int)lsq_q(w2[(ct * 16 + m) * 9 + tap], aw2[0]);
                v = (unsigned long long)(unsigned)(q & 255) << (8 * j);
            }
        }
        w2d[i] = (long)v;
    } else if (id < 25920) {                // conv1 fused constants
        int c = id - 25344;
        float s = g1[c] / sqrtf(v1[c] + EPSF);
        float A = aw1[0] * ax1[0];
        float inv = 1.0f / ax2[0];          // exact (alpha = pow2)
        s1b1[c] = A * s * inv;
        s1b1[576 + c] = (b1[c] - m1[c] * s) * inv;
    } else if (id < 26496) {                // dw fused constants
        int c = id - 25920;
        float s = g2[c] / sqrtf(v2[c] + EPSF);
        float A = ax2[0] * aw2[0];
        float inv = 1.0f / ax3[0];
        s2b2[c] = A * s * inv;
        s2b2[576 + c] = (b2[c] - m2[c] * s) * inv;
    } else if (id < 26592) {                // conv3 fused constants
        int c = id - 26496;
        float s = g3[c] / sqrtf(v3[c] + EPSF);
        float A = ax3[0] * aw3[0];
        s3b3[c] = A * s;
        s3b3[96 + c] = b3[c] - m3[c] * s;
    }
}

// ---------------- K1: conv1+dw fused, block = (batch, 2-row strip, channel-half) ----
// 896 blocks, 18.2 KB LDS, ONE barrier.  dw output -> global qh2s [slot][n] (coalesced).
__global__ __launch_bounds__(448, 4)
void c1dw_k(const float* __restrict__ x, const long* __restrict__ w1p,
            const long* __restrict__ w2d, const float* __restrict__ ax1,
            const float* __restrict__ s1b1, const float* __restrict__ s2b2,
            unsigned short* __restrict__ qh2s) {
    __shared__ unsigned char h1[120 * H1S];   // 4 slab rows x 30 halo cols, nibbles
    const int tid = threadIdx.x;
    const int w = tid >> 6, l = tid & 63;
    const int quad = l >> 4, c16 = l & 15;
    const int qh = quad >> 1, ql = quad & 1;
    const int b = blockIdx.x;           // batch 0..31
    const int r0 = blockIdx.y * 2;      // first output row of strip
    const int ctb = blockIdx.z * 18;    // channel-tile base (half = 288 ch)

    // ---- Phase A: conv1 (i8 MFMA, A=weights B=acts) -> h1 nibbles ----
    {
        const int lp = w * 16 + c16;                 // 0..111: slab row 0..3, col 0..27
        const int row = lp / 28, col = lp - (lp / 28) * 28;
        const int img_row = r0 - 1 + row;
        const bool vrow = (unsigned)img_row < 28u;
        const int p = min(max(img_row, 0), 27) * 28 + col;
        const float inv1 = 1.0f / ax1[0];            // exact for pow2 alpha

        long bfr[3];
        #pragma unroll
        for (int kc = 0; kc < 3; ++kc) {             // quantize 8 input ch per quad
            const float* xs = x + (b * 96 + kc * 32 + quad * 8) * 784 + p;
            unsigned long long v = 0;
            #pragma unroll
            for (int j = 0; j < 8; ++j) {
                float t = xs[j * 784] * inv1;
                t = fminf(fmaxf(t, -8.0f), 7.0f);
                int q = (int)rintf(t);
                v |= (unsigned long long)(q & 255) << (8 * j);
            }
            bfr[kc] = (long)v;
        }
        const int pos_h = row * 30 + col + 1;        // halo-extended slab index
        #pragma unroll 3
        for (int ctl = 0; ctl < 18; ++ctl) {
            const int ct = ctb + ctl;
            int4v acc; acc[0] = 0; acc[1] = 0; acc[2] = 0; acc[3] = 0;
            #pragma unroll
            for (int kc = 0; kc < 3; ++kc)
                acc = __builtin_amdgcn_mfma_i32_16x16x32_i8(
                    w1p[(ct * 3 + kc) * 64 + l], bfr[kc], acc, 0, 0, 0);
            const int co0 = ct * 16 + quad * 4;      // 4 consecutive co per lane
            float4v S = *(const float4v*)(s1b1 + co0);
            float4v B = *(const float4v*)(s1b1 + 576 + co0);
            int pk = 0;
            #pragma unroll
            for (int rr = 0; rr < 4; ++rr) {
                float t = fmaf((float)acc[rr], S[rr], B[rr]);
                t = fminf(fmaxf(t, 0.0f), 7.0f);     // ReLU6 + quant-clip fused
                pk |= ((int)rintf(t)) << (4 * rr);   // nibble pack (values 0..7)
            }
            pk = vrow ? pk : 0;                      // halo rows outside image = 0
            *(unsigned short*)(h1 + pos_h * H1S + ctl * 8 + quad * 2) = (unsigned short)pk;
        }
    }
    // zero halo COLUMNS (cols 0 and 29 of the 4 slab rows): 8 x 38 dwords = 304 tasks
    if (tid < 304) {
        const int q = tid / 38, word = tid - q * 38;
        const int pos_h = (q >> 1) * 30 + (q & 1) * 29;
        *(int*)(h1 + pos_h * H1S + word * 4) = 0;
    }
    __syncthreads();

    // ---- Phase B: 3x3 depthwise as block-diagonal i8 MFMA -> global qh2s ----
    int boff[5];                                     // per-lane tap offsets (hoisted)
    #pragma unroll
    for (int kc = 0; kc < 5; ++kc) {
        int tap = kc * 2 + qh;
        tap = min(tap, 8);                           // tap 9 has zero weight in w2d
        const int dh = tap / 3 - 1, dc = tap - (tap / 3) * 3 - 1;
        boff[kc] = (dh * 30 + dc) * H1S;
    }
    for (int t = w; t < 72; t += 7) {                // 4 pos-tiles x 18 ch-tiles
        const int pt = t / 18, ctl = t - pt * 18;
        const int ct = ctb + ctl;
        const int pos = pt * 16 + c16;               // 0..63 (56..63 dead)
        const int pc = min(pos, 55);
        const int rA = pc / 28, cA = pc - rA * 28;
        const unsigned char* sbase = h1 + ((rA + 1) * 30 + cA + 1) * H1S + ctl * 8 + ql * 4;
        int4v acc; acc[0] = 0; acc[1] = 0; acc[2] = 0; acc[3] = 0;
        #pragma unroll
        for (int kc = 0; kc < 5; ++kc) {
            const unsigned v = *(const unsigned*)(sbase + boff[kc]);
            const long bf = (long)((((unsigned long long)((v >> 4) & 0x0F0F0F0Fu)) << 32)
                                   | (v & 0x0F0F0F0Fu));
            acc = __builtin_amdgcn_mfma_i32_16x16x32_i8(
                w2d[(ct * 5 + kc) * 64 + l], bf, acc, 0, 0, 0);
        }
        const int c0 = ct * 16 + quad * 4;
        float4v S = *(const float4v*)(s2b2 + c0);
        float4v B = *(const float4v*)(s2b2 + 576 + c0);
        int pk = 0;
        #pragma unroll
        for (int rr = 0; rr < 4; ++rr) {
            float tt = fmaf((float)acc[rr], S[rr], B[rr]);
            tt = fminf(fmaxf(tt, 0.0f), 7.0f);
            pk |= ((int)rintf(tt)) << (4 * rr);      // nibble pack
        }
        if (pos < 56)                                 // slot = c0/4; coalesced over c16
            qh2s[(ct * 4 + quad) * 25088 + b * 784 + r0 * 28 + pos] = (unsigned short)pk;
    }
}

// ---------------- K2: conv3 (i8 MFMA) + BN + residual, barrier-free, LDS-free ----
// grid 1568 n-tiles of 16, block 384 (wave w = co-tile).  A-frags: 2 coalesced ushort
// loads from qh2s + lo/hi nibble unpack (perm folded into w3p).
__global__ __launch_bounds__(384, 4)
void conv3_k(const unsigned short* __restrict__ qh2s, const long* __restrict__ w3p,
             const float* __restrict__ x, const float* __restrict__ s3b3,
             float* __restrict__ out) {
    const int tid = threadIdx.x;
    const int w = tid >> 6, l = tid & 63;
    const int quad = l >> 4, c16 = l & 15;
    const int n0 = blockIdx.x * 16;
    const int n = n0 + c16;                          // A-row (m = lane&15)

    int4v acc; acc[0] = 0; acc[1] = 0; acc[2] = 0; acc[3] = 0;
    #pragma unroll 6
    for (int kc = 0; kc < 18; ++kc) {
        const int s0 = kc * 8 + quad * 2;            // slot of channels kc*32+quad*8
        const unsigned u0 = qh2s[s0 * 25088 + n];
        const unsigned u1 = qh2s[(s0 + 1) * 25088 + n];
        const unsigned v = u0 | (u1 << 16);
        const long a = (long)((((unsigned long long)((v >> 4) & 0x0F0F0F0Fu)) << 32)
                              | (v & 0x0F0F0F0Fu));
        acc = __builtin_amdgcn_mfma_i32_16x16x32_i8(
            a, w3p[(w * 18 + kc) * 64 + l], acc, 0, 0, 0);
    }

    const int co = w * 16 + c16;
    const float S = s3b3[co], Bv = s3b3[96 + co];
    const int nb = n0 + quad * 4;                    // 4 consecutive n, same image
    const int bi = nb / 784, p0 = nb - bi * 784;
    const int off = (bi * 96 + co) * 784 + p0;       // 16B-aligned
    const float4v xr = *(const float4v*)(x + off);
    float4v o;
    #pragma unroll
    for (int rr = 0; rr < 4; ++rr)
        o[rr] = fmaf((float)acc[rr], S, Bv) + xr[rr];
    *(float4v*)(out + off) = o;
}

extern "C" void kernel_launch(void* const* d_in, const int* in_sizes, int n_in,
                              void* d_out, int out_size, void* d_ws, size_t ws_size,
                              hipStream_t stream) {
    const float* x   = (const float*)d_in[0];
    const float* w1  = (const float*)d_in[1];
    const float* w2  = (const float*)d_in[2];
    const float* w3  = (const float*)d_in[3];
    const float* aw1 = (const float*)d_in[4];
    const float* ax1 = (const float*)d_in[5];
    const float* g1  = (const float*)d_in[6];
    const float* b1  = (const float*)d_in[7];
    const float* m1  = (const float*)d_in[8];
    const float* v1  = (const float*)d_in[9];
    const float* aw2 = (const float*)d_in[10];
    const float* ax2 = (const float*)d_in[11];
    const float* g2  = (const float*)d_in[12];
    const float* b2  = (const float*)d_in[13];
    const float* m2  = (const float*)d_in[14];
    const float* v2  = (const float*)d_in[15];
    const float* aw3 = (const float*)d_in[16];
    const float* ax3 = (const float*)d_in[17];
    const float* g3  = (const float*)d_in[18];
    const float* b3  = (const float*)d_in[19];
    const float* m3  = (const float*)d_in[20];
    const float* v3  = (const float*)d_in[21];

    char* ws = (char*)d_ws;
    unsigned short* qh2s = (unsigned short*)(ws + QH2S_OFF);
    long* w1p = (long*)(ws + W1P_OFF);
    long* w3p = (long*)(ws + W3P_OFF);
    long* w2d = (long*)(ws + W2D_OFF);
    float* s1b1 = (float*)(ws + S1B1_OFF);
    float* s2b2 = (float*)(ws + S2B2_OFF);
    float* s3b3 = (float*)(ws + S3B3_OFF);

    float* out = (float*)d_out;

    prep_w<<<104, 256, 0, stream>>>(w1, w2, w3, aw1, ax1, ax2, aw2, ax3, aw3,
                                    g1, b1, m1, v1, g2, b2, m2, v2, g3, b3, m3, v3,
                                    w1p, w3p, w2d, s1b1, s2b2, s3b3);
    dim3 g1d(32, 14, 2);
    c1dw_k<<<g1d, 448, 0, stream>>>(x, w1p, w2d, ax1, s1b1, s2b2, qh2s);
    conv3_k<<<1568, 384, 0, stream>>>(qh2s, w3p, x, s3b3, out);
}